// Round 3
// baseline (192.297 us; speedup 1.0000x reference)
//
#include <hip/hip_runtime.h>
#include <math.h>

typedef _Float16 f16x8 __attribute__((ext_vector_type(8)));
typedef float f32x4 __attribute__((ext_vector_type(4)));

#define CIN 8
#define HIN 128
#define WIN 128
#define OH 126
#define OW 126
#define COUT 64
#define NB 128
#define NGROUPS 16
#define CPG 4
#define PWN 31
#define XROWS 34   // real taps reach row 28+3+2=33; padded khw>=9 clamped

// workspace layout
// f16 ext plane [b][wy][wx][c] | f32 partials [b][g][tile16][{s,sq}]
#define NPOOL (NB*PWN*PWN*COUT)          // 7,872,512 f16 elements
#define OFF_PART (NPOOL/2)               // float offset

// Conv via MFMA implicit GEMM — R13 "strip" restructure.
// Change vs R0: MFMA M-dim = 16 consecutive x at one y (a strip), not the
// 16 pixels of one 4x4 window. C-layout (col=lane&15=channel,
// row=(lane>>4)*4+reg = x-offset) then gives lane (q,ln) the 4 x-positions
// of pool window wx=q; iterating the 4 strip rows of a band accumulates the
// window's full 16 values IN-LANE. This deletes the per-window epilogue's
// 8 __shfl_xor (ds_bpermute, ~120cyc, lgkm-serialized with the A-frag
// ds_reads) and 3 selects — the R0 profile's dominant stall candidate
// (waves ~90% stalled at 39% occupancy; more waves in R1 didn't help =>
// per-wave serial chain, not capacity). MFMA count unchanged (12/window).
// Output store bounces through 512B LDS/wave to keep one coalesced 512B
// wave-store per band.
__global__ __launch_bounds__(256)
void conv_mfma_kernel(const float* __restrict__ x,
                      const float* __restrict__ w,
                      const float* __restrict__ bias,
                      const float* __restrict__ gnw,
                      const float* __restrict__ scale,
                      float* __restrict__ ws)
{
  __shared__ __align__(16) _Float16 xs[XROWS*34*8];   // 18,496 B
  __shared__ __align__(16) _Float16 wls[9*64*8];      //  9,216 B
  __shared__ __align__(8)  _Float16 sbuf[4][256];     //  2,048 B
  __shared__ float red[4][16][2];                     //    512 B

  const int tid  = threadIdx.x;
  const int lane = tid & 63, wave = tid >> 6;
  const int tileIdx = blockIdx.x;          // 0..15
  const int tx = tileIdx & 3, ty = tileIdx >> 2;
  const int b  = blockIdx.y;
  const int ox0 = tx*32, oy0 = ty*32;

  // ---- stage weights [khw 9][n 64][ci 8] ----
  for (int idx = tid; idx < 9*64*8; idx += 256) {
    const int ci = idx & 7, n = (idx >> 3) & 63, khw = idx >> 9;
    wls[idx] = (_Float16)w[(n*CIN + ci)*9 + khw];
  }

  // ---- stage x tile: pack 8 ci -> one b128 write per pixel ----
  const float* xb = x + (size_t)b * CIN*HIN*WIN;
  for (int p = tid; p < XROWS*34; p += 256) {
    const int r = p / 34, c = p - r*34;
    const int iy = oy0 + r, ix = ox0 + c;
    const bool ok = (iy < HIN) && (ix < WIN);
    const int gbase = iy*WIN + ix;
    f16x8 pk;
    #pragma unroll
    for (int ci = 0; ci < 8; ++ci) {
      const float v = ok ? xb[ci*HIN*WIN + gbase] : 0.f;
      pk[ci] = (_Float16)v;
    }
    *(f16x8*)&xs[p*8] = pk;
  }
  __syncthreads();

  const int q = lane >> 4, ln = lane & 15;

  // B fragments: chunks c=0,1 from LDS; c=2 is khw=8 for q==0, zero otherwise
  f16x8 bf[4][3];
  #pragma unroll
  for (int nt = 0; nt < 4; ++nt) {
    #pragma unroll
    for (int c = 0; c < 2; ++c)
      bf[nt][c] = *(const f16x8*)&wls[((c*4 + q)*64 + nt*16 + ln)*8];
    if (q == 0)
      bf[nt][2] = *(const f16x8*)&wls[((8)*64 + nt*16 + ln)*8];
    else
      bf[nt][2] = (f16x8){0,0,0,0,0,0,0,0};
  }

  // per-lane A offsets. A lane map for a strip: m = lane&15 = x-offset,
  // k-quad = lane>>4 -> khw = c*4+q, 8 ci contiguous.
  int aoff[3];
  #pragma unroll
  for (int c = 0; c < 3; ++c) {
    const int khw = c*4 + q;               // 0..11
    const int ky = khw / 3, kx = khw - 3*(khw/3);
    aoff[c] = (khw < 9) ? (ky*34 + kx + ln)*8 : ln*8;  // clamp padded taps (B=0 there)
  }

  float bias_r[4], sgn[4];
  #pragma unroll
  for (int nt = 0; nt < 4; ++nt) {
    const int c = nt*16 + ln;
    bias_r[nt] = bias[c];
    sgn[nt] = (gnw[c]*scale[c] >= 0.f) ? 1.f : -1.f;  // GN slope sign (inv>0)
  }

  float s[4]  = {0.f,0.f,0.f,0.f};
  float sq[4] = {0.f,0.f,0.f,0.f};
  _Float16* wext = (_Float16*)ws;

  // x-validity for xedge bands: positions 14,15 of the strip (q==3, r>=2)
  // are conv-x 126,127 -> excluded from stats.
  const float xm_hi = (q < 3) ? 1.f : 0.f;

  // 4 bands per wave: wy_l in {2*wave, 2*wave+1}, x0 in {0,16}.
  // Each band = 4 strips (y = wy*4+sy) covering 4 pool windows (wx=q).
  for (int bd = 0; bd < 4; ++bd) {
    const int wy_l = wave*2 + (bd >> 1);
    const int x0   = (bd & 1) << 4;
    const int wy_g = ty*8 + wy_l;
    const bool xedge = (tx == 3) && (x0 == 16);

    float mx[4] = {-1e30f, -1e30f, -1e30f, -1e30f};

    #pragma unroll
    for (int sy = 0; sy < 4; ++sy) {
      const int y_l = wy_l*4 + sy;
      if (oy0 + y_l >= OH) break;          // uniform; only ty==3, wy_l==7, sy>=2
      const int base = (y_l*34 + x0)*8;

      f32x4 acc[4];
      #pragma unroll
      for (int nt = 0; nt < 4; ++nt) {
        const float bv = bias_r[nt];
        acc[nt] = (f32x4){bv, bv, bv, bv}; // bias as MFMA C operand
      }
      #pragma unroll
      for (int c = 0; c < 3; ++c) {
        const f16x8 a = *(const f16x8*)&xs[base + aoff[c]];
        #pragma unroll
        for (int nt = 0; nt < 4; ++nt)
          acc[nt] = __builtin_amdgcn_mfma_f32_16x16x32_f16(a, bf[nt][c], acc[nt], 0, 0, 0);
      }

      // fully in-lane epilogue: stats + running window max (sign-domain)
      #pragma unroll
      for (int nt = 0; nt < 4; ++nt) {
        float v0 = acc[nt][0], v1 = acc[nt][1];
        float v2 = acc[nt][2], v3 = acc[nt][3];
        if (xedge) { v2 *= xm_hi; v3 *= xm_hi; }   // mask conv-x 126,127
        s[nt]  += (v0+v1) + (v2+v3);
        sq[nt] += v0*v0 + v1*v1 + v2*v2 + v3*v3;
        const float sg = sgn[nt];
        const float m = fmaxf(fmaxf(sg*v0, sg*v1), fmaxf(sg*v2, sg*v3));
        mx[nt] = fmaxf(mx[nt], m);
      }
    }

    // store band's 4 pooled windows: LDS bounce -> one coalesced 512B store
    if (wy_g < PWN) {
      #pragma unroll
      for (int nt = 0; nt < 4; ++nt)
        sbuf[wave][q*64 + nt*16 + ln] = (_Float16)(sgn[nt]*mx[nt]);
      // in-wave LDS RAW: compiler inserts lgkmcnt wait
      const int nw = xedge ? 3 : 4;        // window wx_g==31 dropped
      if (lane < nw*16) {
        const int wx0_g = tx*8 + (x0 >> 2);
        const uint2 v = *(const uint2*)&sbuf[wave][lane*4];
        *(uint2*)&wext[(((size_t)b*PWN + wy_g)*PWN + wx0_g)*COUT + lane*4] = v;
      }
    }
  }

  // per-wave stat reduce: q-groups (xor 16,32) then channels-in-group (xor 1,2)
  #pragma unroll
  for (int nt = 0; nt < 4; ++nt) {
    float a = s[nt], c2 = sq[nt];
    a  += __shfl_xor(a, 16, 64);  a  += __shfl_xor(a, 32, 64);
    a  += __shfl_xor(a, 1, 64);   a  += __shfl_xor(a, 2, 64);
    c2 += __shfl_xor(c2, 16, 64); c2 += __shfl_xor(c2, 32, 64);
    c2 += __shfl_xor(c2, 1, 64);  c2 += __shfl_xor(c2, 2, 64);
    if (lane < 16 && (lane & 3) == 0) {
      red[wave][nt*4 + (ln >> 2)][0] = a;
      red[wave][nt*4 + (ln >> 2)][1] = c2;
    }
  }
  __syncthreads();
  if (tid < 32) {
    const int g = tid >> 1, k = tid & 1;
    const float t = red[0][g][k] + red[1][g][k] + red[2][g][k] + red[3][g][k];
    ws[OFF_PART + (((size_t)b*NGROUPS + g)*16 + tileIdx)*2 + k] = t;
  }
}

// Fused tail: one kernel, 2048 independent blocks (b, xb). Each block
// redundantly computes its batch's GN affine from the L2-hot 1KB partials
// (no cross-block sync, no flags), then applies affine+clamp+NCHW-transpose
// for 2 pooled rows.
__global__ __launch_bounds__(256)
void tail_kernel(const float* __restrict__ gnw,
                 const float* __restrict__ gnb,
                 const float* __restrict__ scale,
                 const float* __restrict__ ws,
                 float* __restrict__ out)
{
  __shared__ float stat[NGROUPS*2];   // [g][{sum,sumsq}]
  __shared__ float AB[128];           // A[64] | B[64]
  __shared__ float vout[COUT*PWN];    // [c][wx], stride 31 -> conflict-free

  const int tid = threadIdx.x;
  const int xb  = blockIdx.x;   // 0..15 -> rows 2*xb, 2*xb+1 (skip >=31)
  const int b   = blockIdx.y;

  if (tid < 32) {
    const int g = tid >> 1, k = tid & 1;
    const float* p = ws + OFF_PART + (size_t)(b*NGROUPS + g)*32 + k;
    float a = 0.f;
    #pragma unroll
    for (int t = 0; t < 16; ++t) a += p[t*2];
    stat[g*2 + k] = a;
  }
  __syncthreads();
  if (tid < COUT) {
    const int c = tid, g = c >> 2;
    const float N = (float)(CPG * OH * OW);
    const float mean = stat[g*2] / N;
    const float var  = stat[g*2 + 1] / N - mean*mean;
    const float inv  = rsqrtf(var + 1e-5f);
    const float ag   = inv * gnw[c];
    AB[c]      = ag * scale[c];
    AB[64 + c] = (gnb[c] - mean * ag) * scale[c];
  }
  __syncthreads();

  const _Float16* wext = (const _Float16*)ws;
  #pragma unroll
  for (int r = 0; r < 2; ++r) {
    const int wy = xb*2 + r;
    if (wy >= PWN) break;
    const size_t rb = (size_t)(b*PWN + wy)*PWN*COUT;   // f16 elements

    if (tid < 248) {                       // 248*8 = 1984 ext elems
      const f16x8 e = *(const f16x8*)&wext[rb + tid*8];
      const int wx = tid >> 3, c0 = (tid & 7)*8;
      #pragma unroll
      for (int j = 0; j < 8; ++j) {
        const int c = c0 + j;
        float v = fmaf(AB[c], (float)e[j], AB[64 + c]);
        v = fminf(fmaxf(v, 0.f), 1.f);
        vout[c*PWN + wx] = v;
      }
    }
    __syncthreads();
    for (int e = tid; e < COUT*PWN; e += 256) {
      const int c = e / PWN, wx = e - c*PWN;
      out[(((size_t)b*COUT + c)*PWN + wy)*PWN + wx] = vout[e];
    }
    __syncthreads();
  }
}

extern "C" void kernel_launch(void* const* d_in, const int* in_sizes, int n_in,
                              void* d_out, int out_size, void* d_ws, size_t ws_size,
                              hipStream_t stream)
{
  const float* x     = (const float*)d_in[0];
  const float* cw    = (const float*)d_in[1];
  const float* cb    = (const float*)d_in[2];
  const float* gnw   = (const float*)d_in[3];
  const float* gnb   = (const float*)d_in[4];
  const float* scale = (const float*)d_in[5];
  float* out = (float*)d_out;
  float* ws  = (float*)d_ws;

  dim3 gridA(16, NB, 1);
  conv_mfma_kernel<<<gridA, 256, 0, stream>>>(x, cw, cb, gnw, scale, ws);

  dim3 gridT(16, NB, 1);
  tail_kernel<<<gridT, 256, 0, stream>>>(gnw, gnb, scale, ws, out);
}

// Round 4
// 176.977 us; speedup vs baseline: 1.0866x; 1.0866x over previous
//
#include <hip/hip_runtime.h>
#include <math.h>

typedef _Float16 f16x8 __attribute__((ext_vector_type(8)));
typedef float f32x4 __attribute__((ext_vector_type(4)));

#define CIN 8
#define HIN 128
#define WIN 128
#define OH 126
#define OW 126
#define COUT 64
#define NB 128
#define NGROUPS 16
#define CPG 4
#define PWN 31
#define XROWS 34
#define XH_DIM 130            // padded image (2 halo rows/cols of zeros)
#define TPIX (34*34)          // 1156 pixels per tile

// ---- new ws layout (bytes) ----
// [0, XH)           : xh  f16 [b][iy 0..129][ix 0..129][ci 8]
// [XH, XH+WEXT)     : wext f16 [b][wy][wx][c]
// [XH+WEXT, ..)     : partials f32 [b][g][4 cols][{s,sq}]
#define XH_BYTES   ((size_t)NB*XH_DIM*XH_DIM*CIN*2)          // 34,611,200
#define WEXT_BYTES ((size_t)NB*PWN*PWN*COUT*2)               // 15,745,024
#define PART_BYTES ((size_t)NB*NGROUPS*4*2*4)                //     65,536
#define WS_NEEDED  (XH_BYTES + WEXT_BYTES + PART_BYTES)      // 50,421,760

// ---- old (fallback) ws layout ----
#define NPOOL (NB*PWN*PWN*COUT)
#define OFF_PART_OLD (NPOOL/2)   // f32 offset

// ============================================================
// Pre-pack: x f32 NCHW -> xh f16 [b][iy][ix][ci] with zero halo.
// Pure memory-bound (~99MB); removes ALL cvt/pack/boundary VALU
// from the conv kernel and enables global_load_lds DMA staging.
// ============================================================
__global__ __launch_bounds__(192)
void xpack_kernel(const float* __restrict__ x, _Float16* __restrict__ xh)
{
  const int iy = blockIdx.x;      // 0..129
  const int b  = blockIdx.y;
  const int ix = threadIdx.x;     // active < 130
  if (ix >= XH_DIM) return;
  f16x8 pk = {0,0,0,0,0,0,0,0};
  if (iy < HIN && ix < WIN) {
    const float* xb = x + (size_t)b*CIN*HIN*WIN + iy*WIN + ix;
    #pragma unroll
    for (int ci = 0; ci < 8; ++ci)
      pk[ci] = (_Float16)xb[ci*HIN*WIN];
  }
  *(f16x8*)&xh[(((size_t)b*XH_DIM + iy)*XH_DIM + ix)*CIN] = pk;
}

// ============================================================
// Pipelined conv: 512 threads (8 waves), grid (4, NB).
// Block = one tile-column (tx fixed), chains ty = 0..3 with
// double-buffered LDS staged by global_load_lds dwordx4 DMA.
// DMA for tile ty+1 is issued BEFORE computing tile ty; the
// only wait is vmcnt(0) at the tile boundary -> staging latency
// hides under MFMA. Hot loop = R0's proven window epilogue.
// Stats accumulate across the whole column -> 4 partials/batch.
// ============================================================
__global__ __launch_bounds__(512)
void conv_dma_kernel(const _Float16* __restrict__ xh,
                     const float* __restrict__ w,
                     const float* __restrict__ bias,
                     const float* __restrict__ gnw,
                     const float* __restrict__ scale,
                     _Float16* __restrict__ wext,
                     float* __restrict__ parts)
{
  __shared__ __align__(16) _Float16 xs[2][TPIX*8];    // 2 x 18,496 B
  __shared__ __align__(16) _Float16 wls[9*64*8];      //     9,216 B
  __shared__ float red[8][16][2];                     //     1,024 B

  const int tid  = threadIdx.x;
  const int lane = tid & 63, wave = tid >> 6;   // 8 waves
  const int tx = blockIdx.x;                    // 0..3 (tile column)
  const int b  = blockIdx.y;
  const int ox0 = tx*32;

  // ---- stage weights [khw 9][n 64][ci 8] (once per block) ----
  for (int idx = tid; idx < 9*64*8; idx += 512) {
    const int ci = idx & 7, n = (idx >> 3) & 63, khw = idx >> 9;
    wls[idx] = (_Float16)w[(n*CIN + ci)*9 + khw];
  }

  const int q = lane >> 4, ln = lane & 15;

  // DMA one tile into xs[buf]: one f16x8 pixel per lane per instr.
  // p = k*512 + tid -> LDS byte addr = uniform_base + lane*16  (required)
  // global src is per-lane (padded xh -> no boundary logic).
  auto stage = [&](int buf, int ty) {
    const int oy0 = ty*32;
    #pragma unroll
    for (int k = 0; k < 3; ++k) {
      const int p = k*512 + tid;
      if (p < TPIX) {
        const int r = p / 34, c = p - r*34;
        const size_t gb = (((size_t)b*XH_DIM + (oy0 + r))*XH_DIM + (ox0 + c))*CIN;
        __builtin_amdgcn_global_load_lds(
            (const __attribute__((address_space(1))) void*)(xh + gb),
            (__attribute__((address_space(3))) void*)&xs[buf][p*8],
            16, 0, 0);
      }
    }
  };

  stage(0, 0);

  // B fragments load after the barrier (wls ready then); issue DMA first.
  asm volatile("s_waitcnt vmcnt(0)" ::: "memory");
  __syncthreads();

  f16x8 bf[4][3];
  #pragma unroll
  for (int nt = 0; nt < 4; ++nt) {
    #pragma unroll
    for (int c = 0; c < 2; ++c)
      bf[nt][c] = *(const f16x8*)&wls[((c*4 + q)*64 + nt*16 + ln)*8];
    if (q == 0)
      bf[nt][2] = *(const f16x8*)&wls[((8)*64 + nt*16 + ln)*8];
    else
      bf[nt][2] = (f16x8){0,0,0,0,0,0,0,0};
  }

  // per-lane A offsets (window-centric lane map: m = lane&15 pixel-in-window)
  const int dy = ln >> 2, dx = ln & 3;
  int aoff[3];
  #pragma unroll
  for (int c = 0; c < 3; ++c) {
    const int khw = c*4 + q;               // 0..11
    const int ky = khw / 3, kx = khw - 3*(khw/3);
    aoff[c] = (khw < 9) ? ((dy + ky)*34 + (dx + kx))*8 : 0;  // padded taps -> B=0
  }

  float bias_r[4], sgn[4];
  #pragma unroll
  for (int nt = 0; nt < 4; ++nt) {
    const int c = nt*16 + ln;
    bias_r[nt] = bias[c];
    sgn[nt] = (gnw[c]*scale[c] >= 0.f) ? 1.f : -1.f;  // GN slope sign (inv>0)
  }

  float s[4]  = {0.f,0.f,0.f,0.f};
  float sq[4] = {0.f,0.f,0.f,0.f};

  for (int ty = 0; ty < 4; ++ty) {
    const int cur = ty & 1;
    if (ty < 3) stage(cur ^ 1, ty + 1);    // async prefetch next tile

    // 8 windows per wave: window-row = wave, 8 cols
    #pragma unroll 2
    for (int i = 0; i < 8; ++i) {
      const int wxl = i;
      const int base = (wave*4*34 + wxl*4)*8;

      f32x4 acc[4];
      #pragma unroll
      for (int nt = 0; nt < 4; ++nt) {
        const float bv = bias_r[nt];
        acc[nt] = (f32x4){bv, bv, bv, bv};  // bias as MFMA C operand
      }
      #pragma unroll
      for (int c = 0; c < 3; ++c) {
        const f16x8 a = *(const f16x8*)&xs[cur][base + aoff[c]];
        #pragma unroll
        for (int nt = 0; nt < 4; ++nt)
          acc[nt] = __builtin_amdgcn_mfma_f32_16x16x32_f16(a, bf[nt][c], acc[nt], 0, 0, 0);
      }

      const int wyg = ty*8 + wave, wxg = tx*8 + wxl;
      if ((wyg < PWN) && (wxg < PWN)) {
        const size_t rowbase = ((size_t)(b*PWN + wyg)*PWN + wxg)*COUT;
        float m4[4];
        #pragma unroll
        for (int nt = 0; nt < 4; ++nt) {
          const float v0 = acc[nt][0], v1 = acc[nt][1];
          const float v2 = acc[nt][2], v3 = acc[nt][3];
          s[nt]  += (v0+v1) + (v2+v3);
          sq[nt] += v0*v0 + v1*v1 + v2*v2 + v3*v3;
          const float sg = sgn[nt];
          float m = fmaxf(fmaxf(sg*v0, sg*v1), fmaxf(sg*v2, sg*v3));
          m = fmaxf(m, __shfl_xor(m, 16, 64));
          m = fmaxf(m, __shfl_xor(m, 32, 64));
          m4[nt] = sg*m;
        }
        // lane L stores channel c=L: one full-wave 128B store
        float mv = m4[0];
        mv = (q == 1) ? m4[1] : mv;
        mv = (q == 2) ? m4[2] : mv;
        mv = (q == 3) ? m4[3] : mv;
        wext[rowbase + lane] = (_Float16)mv;
      } else {
        // edge windows (wyg==31 or wxg==31): stats only, masked to 126x126
        const bool yv = (wyg*4 + q) < OH;
        #pragma unroll
        for (int nt = 0; nt < 4; ++nt) {
          #pragma unroll
          for (int r = 0; r < 4; ++r) {
            const bool okp = yv && (wxg*4 + r < OW);
            const float v = okp ? acc[nt][r] : 0.f;
            s[nt] += v; sq[nt] += v*v;
          }
        }
      }
    }

    if (ty < 3) {
      asm volatile("s_waitcnt vmcnt(0)" ::: "memory");  // DMA of next tile done
      __syncthreads();                                   // visible to all waves
    }
  }

  // per-wave stat reduce: quads (xor 16,32) then channels-in-group (xor 1,2)
  #pragma unroll
  for (int nt = 0; nt < 4; ++nt) {
    float a = s[nt], c2 = sq[nt];
    a  += __shfl_xor(a, 16, 64);  a  += __shfl_xor(a, 32, 64);
    a  += __shfl_xor(a, 1, 64);   a  += __shfl_xor(a, 2, 64);
    c2 += __shfl_xor(c2, 16, 64); c2 += __shfl_xor(c2, 32, 64);
    c2 += __shfl_xor(c2, 1, 64);  c2 += __shfl_xor(c2, 2, 64);
    if (lane < 16 && (lane & 3) == 0) {
      red[wave][nt*4 + (ln >> 2)][0] = a;
      red[wave][nt*4 + (ln >> 2)][1] = c2;
    }
  }
  __syncthreads();
  if (tid < 32) {
    const int g = tid >> 1, k = tid & 1;
    float t = 0.f;
    #pragma unroll
    for (int wv = 0; wv < 8; ++wv) t += red[wv][g][k];
    parts[(((size_t)b*NGROUPS + g)*4 + tx)*2 + k] = t;
  }
}

// ============================================================
// Fallback conv (proven R0/R2 path, old ws layout) — used only
// if ws_size < WS_NEEDED.
// ============================================================
__global__ __launch_bounds__(256)
void conv_mfma_kernel(const float* __restrict__ x,
                      const float* __restrict__ w,
                      const float* __restrict__ bias,
                      const float* __restrict__ gnw,
                      const float* __restrict__ scale,
                      float* __restrict__ ws)
{
  __shared__ __align__(16) _Float16 xs[XROWS*34*8];
  __shared__ __align__(16) _Float16 wls[9*64*8];
  __shared__ float red[4][16][2];

  const int tid  = threadIdx.x;
  const int lane = tid & 63, wave = tid >> 6;
  const int tileIdx = blockIdx.x;
  const int tx = tileIdx & 3, ty = tileIdx >> 2;
  const int b  = blockIdx.y;
  const int ox0 = tx*32, oy0 = ty*32;

  for (int idx = tid; idx < 9*64*8; idx += 256) {
    const int ci = idx & 7, n = (idx >> 3) & 63, khw = idx >> 9;
    wls[idx] = (_Float16)w[(n*CIN + ci)*9 + khw];
  }
  const float* xb = x + (size_t)b * CIN*HIN*WIN;
  for (int p = tid; p < XROWS*34; p += 256) {
    const int r = p / 34, c = p - r*34;
    const int iy = oy0 + r, ix = ox0 + c;
    const bool ok = (iy < HIN) && (ix < WIN);
    const int gbase = iy*WIN + ix;
    f16x8 pk;
    #pragma unroll
    for (int ci = 0; ci < 8; ++ci) {
      const float v = ok ? xb[ci*HIN*WIN + gbase] : 0.f;
      pk[ci] = (_Float16)v;
    }
    *(f16x8*)&xs[p*8] = pk;
  }
  __syncthreads();

  const int q = lane >> 4, ln = lane & 15;
  f16x8 bf[4][3];
  #pragma unroll
  for (int nt = 0; nt < 4; ++nt) {
    #pragma unroll
    for (int c = 0; c < 2; ++c)
      bf[nt][c] = *(const f16x8*)&wls[((c*4 + q)*64 + nt*16 + ln)*8];
    if (q == 0) bf[nt][2] = *(const f16x8*)&wls[((8)*64 + nt*16 + ln)*8];
    else        bf[nt][2] = (f16x8){0,0,0,0,0,0,0,0};
  }
  const int dy = ln >> 2, dx = ln & 3;
  int aoff[3];
  #pragma unroll
  for (int c = 0; c < 3; ++c) {
    const int khw = c*4 + q;
    const int ky = khw / 3, kx = khw - 3*(khw/3);
    aoff[c] = (khw < 9) ? ((dy + ky)*34 + (dx + kx))*8 : 0;
  }
  float bias_r[4], sgn[4];
  #pragma unroll
  for (int nt = 0; nt < 4; ++nt) {
    const int c = nt*16 + ln;
    bias_r[nt] = bias[c];
    sgn[nt] = (gnw[c]*scale[c] >= 0.f) ? 1.f : -1.f;
  }
  float s[4]  = {0.f,0.f,0.f,0.f};
  float sq[4] = {0.f,0.f,0.f,0.f};
  _Float16* wext = (_Float16*)ws;

  #pragma unroll 2
  for (int i = 0; i < 16; ++i) {
    const int wyl = wave*2 + (i >> 3), wxl = i & 7;
    const int base = (wyl*4*34 + wxl*4)*8;
    f32x4 acc[4];
    #pragma unroll
    for (int nt = 0; nt < 4; ++nt) {
      const float bv = bias_r[nt];
      acc[nt] = (f32x4){bv, bv, bv, bv};
    }
    #pragma unroll
    for (int c = 0; c < 3; ++c) {
      const f16x8 a = *(const f16x8*)&xs[base + aoff[c]];
      #pragma unroll
      for (int nt = 0; nt < 4; ++nt)
        acc[nt] = __builtin_amdgcn_mfma_f32_16x16x32_f16(a, bf[nt][c], acc[nt], 0, 0, 0);
    }
    const int wyg = ty*8 + wyl, wxg = tx*8 + wxl;
    if ((wyg < PWN) && (wxg < PWN)) {
      const size_t rowbase = ((size_t)(b*PWN + wyg)*PWN + wxg)*COUT;
      float m4[4];
      #pragma unroll
      for (int nt = 0; nt < 4; ++nt) {
        const float v0 = acc[nt][0], v1 = acc[nt][1];
        const float v2 = acc[nt][2], v3 = acc[nt][3];
        s[nt]  += (v0+v1) + (v2+v3);
        sq[nt] += v0*v0 + v1*v1 + v2*v2 + v3*v3;
        const float sg = sgn[nt];
        float m = fmaxf(fmaxf(sg*v0, sg*v1), fmaxf(sg*v2, sg*v3));
        m = fmaxf(m, __shfl_xor(m, 16, 64));
        m = fmaxf(m, __shfl_xor(m, 32, 64));
        m4[nt] = sg*m;
      }
      float mv = m4[0];
      mv = (q == 1) ? m4[1] : mv;
      mv = (q == 2) ? m4[2] : mv;
      mv = (q == 3) ? m4[3] : mv;
      wext[rowbase + lane] = (_Float16)mv;
    } else {
      const bool yv = (wyg*4 + q) < OH;
      #pragma unroll
      for (int nt = 0; nt < 4; ++nt) {
        #pragma unroll
        for (int r = 0; r < 4; ++r) {
          const bool okp = yv && (wxg*4 + r < OW);
          const float v = okp ? acc[nt][r] : 0.f;
          s[nt] += v; sq[nt] += v*v;
        }
      }
    }
  }
  #pragma unroll
  for (int nt = 0; nt < 4; ++nt) {
    float a = s[nt], c2 = sq[nt];
    a  += __shfl_xor(a, 16, 64);  a  += __shfl_xor(a, 32, 64);
    a  += __shfl_xor(a, 1, 64);   a  += __shfl_xor(a, 2, 64);
    c2 += __shfl_xor(c2, 16, 64); c2 += __shfl_xor(c2, 32, 64);
    c2 += __shfl_xor(c2, 1, 64);  c2 += __shfl_xor(c2, 2, 64);
    if (lane < 16 && (lane & 3) == 0) {
      red[wave][nt*4 + (ln >> 2)][0] = a;
      red[wave][nt*4 + (ln >> 2)][1] = c2;
    }
  }
  __syncthreads();
  if (tid < 32) {
    const int g = tid >> 1, k = tid & 1;
    const float t = red[0][g][k] + red[1][g][k] + red[2][g][k] + red[3][g][k];
    ws[OFF_PART_OLD + (((size_t)b*NGROUPS + g)*16 + tileIdx)*2 + k] = t;
  }
}

// ============================================================
// Fused tail (parameterized partial count / pointers).
// ============================================================
__global__ __launch_bounds__(256)
void tail_kernel(const float* __restrict__ gnw,
                 const float* __restrict__ gnb,
                 const float* __restrict__ scale,
                 const _Float16* __restrict__ wext,
                 const float* __restrict__ parts,
                 const int nparts,
                 float* __restrict__ out)
{
  __shared__ float stat[NGROUPS*2];
  __shared__ float AB[128];
  __shared__ float vout[COUT*PWN];

  const int tid = threadIdx.x;
  const int xb  = blockIdx.x;
  const int b   = blockIdx.y;

  if (tid < 32) {
    const int g = tid >> 1, k = tid & 1;
    const float* p = parts + ((size_t)(b*NGROUPS + g)*nparts)*2 + k;
    float a = 0.f;
    for (int t = 0; t < nparts; ++t) a += p[t*2];
    stat[g*2 + k] = a;
  }
  __syncthreads();
  if (tid < COUT) {
    const int c = tid, g = c >> 2;
    const float N = (float)(CPG * OH * OW);
    const float mean = stat[g*2] / N;
    const float var  = stat[g*2 + 1] / N - mean*mean;
    const float inv  = rsqrtf(var + 1e-5f);
    const float ag   = inv * gnw[c];
    AB[c]      = ag * scale[c];
    AB[64 + c] = (gnb[c] - mean * ag) * scale[c];
  }
  __syncthreads();

  #pragma unroll
  for (int r = 0; r < 2; ++r) {
    const int wy = xb*2 + r;
    if (wy >= PWN) break;
    const size_t rb = (size_t)(b*PWN + wy)*PWN*COUT;

    if (tid < 248) {
      const f16x8 e = *(const f16x8*)&wext[rb + tid*8];
      const int wx = tid >> 3, c0 = (tid & 7)*8;
      #pragma unroll
      for (int j = 0; j < 8; ++j) {
        const int c = c0 + j;
        float v = fmaf(AB[c], (float)e[j], AB[64 + c]);
        v = fminf(fmaxf(v, 0.f), 1.f);
        vout[c*PWN + wx] = v;
      }
    }
    __syncthreads();
    for (int e = tid; e < COUT*PWN; e += 256) {
      const int c = e / PWN, wx = e - c*PWN;
      out[(((size_t)b*COUT + c)*PWN + wy)*PWN + wx] = vout[e];
    }
    __syncthreads();
  }
}

extern "C" void kernel_launch(void* const* d_in, const int* in_sizes, int n_in,
                              void* d_out, int out_size, void* d_ws, size_t ws_size,
                              hipStream_t stream)
{
  const float* x     = (const float*)d_in[0];
  const float* cw    = (const float*)d_in[1];
  const float* cb    = (const float*)d_in[2];
  const float* gnw   = (const float*)d_in[3];
  const float* gnb   = (const float*)d_in[4];
  const float* scale = (const float*)d_in[5];
  float* out = (float*)d_out;
  float* ws  = (float*)d_ws;

  if (ws_size >= WS_NEEDED) {
    _Float16* xh   = (_Float16*)ws;
    _Float16* wext = (_Float16*)((char*)ws + XH_BYTES);
    float*    prt  = (float*)((char*)ws + XH_BYTES + WEXT_BYTES);

    xpack_kernel<<<dim3(XH_DIM, NB), 192, 0, stream>>>(x, xh);
    conv_dma_kernel<<<dim3(4, NB), 512, 0, stream>>>(xh, cw, cb, gnw, scale, wext, prt);
    tail_kernel<<<dim3(16, NB), 256, 0, stream>>>(gnw, gnb, scale, wext, prt, 4, out);
  } else {
    conv_mfma_kernel<<<dim3(16, NB), 256, 0, stream>>>(x, cw, cb, gnw, scale, ws);
    tail_kernel<<<dim3(16, NB), 256, 0, stream>>>(gnw, gnb, scale,
                                                  (const _Float16*)ws,
                                                  ws + OFF_PART_OLD, 16, out);
  }
}

// Round 5
// 167.222 us; speedup vs baseline: 1.1500x; 1.0583x over previous
//
#include <hip/hip_runtime.h>
#include <math.h>

typedef _Float16 f16x8 __attribute__((ext_vector_type(8)));
typedef float f32x4 __attribute__((ext_vector_type(4)));

#define CIN 8
#define HIN 128
#define WIN 128
#define OH 126
#define OW 126
#define COUT 64
#define NB 128
#define NGROUPS 16
#define CPG 4
#define PWN 31
#define XROWS 34
#define XH_DIM 130            // padded image (2 halo rows/cols of zeros)
#define TPIX (34*34)          // 1156 pixels per tile
#define XSPAD 3072            // pads LDS to 54.4KB -> 2 blocks/CU -> VGPR budget 128

// ---- ws layout (bytes) ----
// xh f16 [b][iy][ix][ci] | wext f16 [b][wy][wx][c] | parts f32 | wh f16 [khw][n][ci]
#define XH_BYTES   ((size_t)NB*XH_DIM*XH_DIM*CIN*2)          // 34,611,200
#define WEXT_BYTES ((size_t)NB*PWN*PWN*COUT*2)               // 15,745,024
#define PART_BYTES ((size_t)NB*NGROUPS*4*2*4)                //     65,536
#define WH_BYTES   ((size_t)9*64*8*2)                        //      9,216
#define WS_NEEDED  (XH_BYTES + WEXT_BYTES + PART_BYTES + WH_BYTES)

// ---- old (fallback) ws layout ----
#define NPOOL (NB*PWN*PWN*COUT)
#define OFF_PART_OLD (NPOOL/2)   // f32 offset

// ============================================================
// Pre-pack: x f32 NCHW -> xh f16 [b][iy][ix][ci] with zero halo;
// block XH_DIM additionally packs weights -> wh[khw][n][ci] f16.
// ============================================================
__global__ __launch_bounds__(192)
void xpack_kernel(const float* __restrict__ x, const float* __restrict__ w,
                  _Float16* __restrict__ xh, _Float16* __restrict__ wh)
{
  const int iy = blockIdx.x;      // 0..129, 130 = weight block
  const int b  = blockIdx.y;
  if (iy == XH_DIM) {
    if (b != 0) return;
    for (int i = threadIdx.x; i < 9*64*8; i += 192) {
      const int khw = i >> 9, rem = i & 511;      // rem = n*8+ci
      wh[i] = (_Float16)w[rem*9 + khw];
    }
    return;
  }
  const int ix = threadIdx.x;     // active < 130
  if (ix >= XH_DIM) return;
  f16x8 pk = {0,0,0,0,0,0,0,0};
  if (iy < HIN && ix < WIN) {
    const float* xb = x + (size_t)b*CIN*HIN*WIN + iy*WIN + ix;
    #pragma unroll
    for (int ci = 0; ci < 8; ++ci)
      pk[ci] = (_Float16)xb[ci*HIN*WIN];
  }
  *(f16x8*)&xh[(((size_t)b*XH_DIM + iy)*XH_DIM + ix)*CIN] = pk;
}

// ============================================================
// Pipelined conv, strip-mapped (R3-verified lane map, in-lane
// pooling) inside the R4 DMA double-buffer structure.
// R5 changes vs R4, all aimed at the DS pipe (the measured
// bottleneck: 1.97M bank conflicts == per-window B-frag reloads
// at VGPR=72; DS-cycle arithmetic matches the 61us duration):
//  - B fragments load from global wh (L2-hot), wls LDS deleted.
//  - strip mapping: pooling max is IN-LANE; no ds_bpermute per
//    window; store via tiny sbuf bounce (~1.6 DS op/window vs 8+).
//  - LDS padded to 54.4KB: LDS-occupancy 2 blocks/CU -> allocator
//    VGPR budget 128 -> bf[4][3] (48 regs) can stay resident.
//    (512 blocks = 2/CU anyway; zero real occupancy loss.)
// ============================================================
__global__ __launch_bounds__(512)
void conv_dma_kernel(const _Float16* __restrict__ xh,
                     const _Float16* __restrict__ wh,
                     const float* __restrict__ bias,
                     const float* __restrict__ gnw,
                     const float* __restrict__ scale,
                     _Float16* __restrict__ wext,
                     float* __restrict__ parts)
{
  __shared__ __align__(16) _Float16 xs[2][TPIX*8 + XSPAD]; // 2 x 24,640 B
  __shared__ __align__(8)  _Float16 sbuf[8][256];          //   4,096 B
  __shared__ float red[8][16][2];                          //   1,024 B

  const int tid  = threadIdx.x;
  const int lane = tid & 63, wv = tid >> 6;     // 8 waves
  const int tx = blockIdx.x;                    // 0..3 (tile column)
  const int b  = blockIdx.y;
  const int ox0 = tx*32;

  const int q = lane >> 4, ln = lane & 15;

  // DMA one tile into xs[buf]: one f16x8 pixel per lane per instr.
  auto stage = [&](int buf, int ty) {
    const int oy0 = ty*32;
    #pragma unroll
    for (int k = 0; k < 3; ++k) {
      const int p = k*512 + tid;
      if (p < TPIX) {
        const int r = p / 34, c = p - r*34;
        const size_t gb = (((size_t)b*XH_DIM + (oy0 + r))*XH_DIM + (ox0 + c))*CIN;
        __builtin_amdgcn_global_load_lds(
            (const __attribute__((address_space(1))) void*)(xh + gb),
            (__attribute__((address_space(3))) void*)&xs[buf][p*8],
            16, 0, 0);
      }
    }
  };

  stage(0, 0);

  // B fragments straight from global (L2-hot, 9KB total, broadcast).
  f16x8 bf[4][3];
  #pragma unroll
  for (int nt = 0; nt < 4; ++nt) {
    #pragma unroll
    for (int c = 0; c < 2; ++c)
      bf[nt][c] = *(const f16x8*)&wh[((c*4 + q)*64 + nt*16 + ln)*8];
    if (q == 0)
      bf[nt][2] = *(const f16x8*)&wh[((8)*64 + nt*16 + ln)*8];
    else
      bf[nt][2] = (f16x8){0,0,0,0,0,0,0,0};
  }

  // strip A offsets: lane ln = x-offset m, quad q picks khw = c*4+q.
  int aoff[3];
  #pragma unroll
  for (int c = 0; c < 3; ++c) {
    const int khw = c*4 + q;               // 0..11
    const int ky = khw / 3, kx = khw - 3*(khw/3);
    aoff[c] = (khw < 9) ? (ky*34 + kx + ln)*8 : ln*8;  // padded taps -> B=0
  }

  float bias_r[4], sgn[4];
  #pragma unroll
  for (int nt = 0; nt < 4; ++nt) {
    const int c = nt*16 + ln;
    bias_r[nt] = bias[c];
    sgn[nt] = (gnw[c]*scale[c] >= 0.f) ? 1.f : -1.f;  // GN slope sign (inv>0)
  }

  float s[4]  = {0.f,0.f,0.f,0.f};
  float sq[4] = {0.f,0.f,0.f,0.f};

  // stats x-mask: strip positions 14,15 (q==3, regs 2,3) are conv-x
  // 126,127 when tx==3 && x0==16 -> excluded.
  const float xm_hi = (q < 3) ? 1.f : 0.f;

  asm volatile("s_waitcnt vmcnt(0)" ::: "memory");
  __syncthreads();

  for (int ty = 0; ty < 4; ++ty) {
    const int cur = ty & 1;
    if (ty < 3) stage(cur ^ 1, ty + 1);    // async prefetch next tile

    const int wy_g = ty*8 + wv;
    const int oy0  = ty*32;

    // 2 bands per wave (x0 = 0, 16); band = 4 strips = 4 pool windows
    #pragma unroll
    for (int bd = 0; bd < 2; ++bd) {
      const int x0 = bd << 4;
      const bool xedge = (tx == 3) && (bd == 1);

      float mx[4] = {-1e30f, -1e30f, -1e30f, -1e30f};

      #pragma unroll
      for (int sy = 0; sy < 4; ++sy) {
        const int y_l = wv*4 + sy;
        if (oy0 + y_l >= OH) break;        // uniform: only ty==3, wv==7, sy>=2
        const int base = (y_l*34 + x0)*8;

        f32x4 acc[4];
        #pragma unroll
        for (int nt = 0; nt < 4; ++nt) {
          const float bv = bias_r[nt];
          acc[nt] = (f32x4){bv, bv, bv, bv};  // bias as MFMA C operand
        }
        #pragma unroll
        for (int c = 0; c < 3; ++c) {
          const f16x8 a = *(const f16x8*)&xs[cur][base + aoff[c]];
          #pragma unroll
          for (int nt = 0; nt < 4; ++nt)
            acc[nt] = __builtin_amdgcn_mfma_f32_16x16x32_f16(a, bf[nt][c], acc[nt], 0, 0, 0);
        }

        // fully in-lane: stats + running window max (sign-domain)
        #pragma unroll
        for (int nt = 0; nt < 4; ++nt) {
          float v0 = acc[nt][0], v1 = acc[nt][1];
          float v2 = acc[nt][2], v3 = acc[nt][3];
          if (xedge) { v2 *= xm_hi; v3 *= xm_hi; }   // mask conv-x 126,127
          s[nt]  += (v0+v1) + (v2+v3);
          sq[nt] += v0*v0 + v1*v1 + v2*v2 + v3*v3;
          const float sg = sgn[nt];
          const float m = fmaxf(fmaxf(sg*v0, sg*v1), fmaxf(sg*v2, sg*v3));
          mx[nt] = fmaxf(mx[nt], m);
        }
      }

      // store band's 4 pooled windows: sbuf bounce -> coalesced store
      if (wy_g < PWN) {
        #pragma unroll
        for (int nt = 0; nt < 4; ++nt)
          sbuf[wv][q*64 + nt*16 + ln] = (_Float16)(sgn[nt]*mx[nt]);
        const int nw = xedge ? 3 : 4;      // window wx_g==31 dropped
        if (lane < nw*16) {
          const int wx0_g = tx*8 + (x0 >> 2);
          const uint2 v = *(const uint2*)&sbuf[wv][lane*4];
          *(uint2*)&wext[(((size_t)b*PWN + wy_g)*PWN + wx0_g)*COUT + lane*4] = v;
        }
      }
    }

    if (ty < 3) {
      asm volatile("s_waitcnt vmcnt(0)" ::: "memory");  // next tile DMA done
      __syncthreads();                                   // visible to all waves
    }
  }

  // per-wave stat reduce: quads (xor 16,32) then channels-in-group (xor 1,2)
  #pragma unroll
  for (int nt = 0; nt < 4; ++nt) {
    float a = s[nt], c2 = sq[nt];
    a  += __shfl_xor(a, 16, 64);  a  += __shfl_xor(a, 32, 64);
    a  += __shfl_xor(a, 1, 64);   a  += __shfl_xor(a, 2, 64);
    c2 += __shfl_xor(c2, 16, 64); c2 += __shfl_xor(c2, 32, 64);
    c2 += __shfl_xor(c2, 1, 64);  c2 += __shfl_xor(c2, 2, 64);
    if (lane < 16 && (lane & 3) == 0) {
      red[wv][nt*4 + (ln >> 2)][0] = a;
      red[wv][nt*4 + (ln >> 2)][1] = c2;
    }
  }
  __syncthreads();
  if (tid < 32) {
    const int g = tid >> 1, k = tid & 1;
    float t = 0.f;
    #pragma unroll
    for (int w8 = 0; w8 < 8; ++w8) t += red[w8][g][k];
    parts[(((size_t)b*NGROUPS + g)*4 + tx)*2 + k] = t;
  }
}

// ============================================================
// Fallback conv (proven R0/R2 path, old ws layout).
// ============================================================
__global__ __launch_bounds__(256)
void conv_mfma_kernel(const float* __restrict__ x,
                      const float* __restrict__ w,
                      const float* __restrict__ bias,
                      const float* __restrict__ gnw,
                      const float* __restrict__ scale,
                      float* __restrict__ ws)
{
  __shared__ __align__(16) _Float16 xs[XROWS*34*8];
  __shared__ __align__(16) _Float16 wls[9*64*8];
  __shared__ float red[4][16][2];

  const int tid  = threadIdx.x;
  const int lane = tid & 63, wave = tid >> 6;
  const int tileIdx = blockIdx.x;
  const int tx = tileIdx & 3, ty = tileIdx >> 2;
  const int b  = blockIdx.y;
  const int ox0 = tx*32, oy0 = ty*32;

  for (int idx = tid; idx < 9*64*8; idx += 256) {
    const int ci = idx & 7, n = (idx >> 3) & 63, khw = idx >> 9;
    wls[idx] = (_Float16)w[(n*CIN + ci)*9 + khw];
  }
  const float* xb = x + (size_t)b * CIN*HIN*WIN;
  for (int p = tid; p < XROWS*34; p += 256) {
    const int r = p / 34, c = p - r*34;
    const int iy = oy0 + r, ix = ox0 + c;
    const bool ok = (iy < HIN) && (ix < WIN);
    const int gbase = iy*WIN + ix;
    f16x8 pk;
    #pragma unroll
    for (int ci = 0; ci < 8; ++ci) {
      const float v = ok ? xb[ci*HIN*WIN + gbase] : 0.f;
      pk[ci] = (_Float16)v;
    }
    *(f16x8*)&xs[p*8] = pk;
  }
  __syncthreads();

  const int q = lane >> 4, ln = lane & 15;
  f16x8 bf[4][3];
  #pragma unroll
  for (int nt = 0; nt < 4; ++nt) {
    #pragma unroll
    for (int c = 0; c < 2; ++c)
      bf[nt][c] = *(const f16x8*)&wls[((c*4 + q)*64 + nt*16 + ln)*8];
    if (q == 0) bf[nt][2] = *(const f16x8*)&wls[((8)*64 + nt*16 + ln)*8];
    else        bf[nt][2] = (f16x8){0,0,0,0,0,0,0,0};
  }
  const int dy = ln >> 2, dx = ln & 3;
  int aoff[3];
  #pragma unroll
  for (int c = 0; c < 3; ++c) {
    const int khw = c*4 + q;
    const int ky = khw / 3, kx = khw - 3*(khw/3);
    aoff[c] = (khw < 9) ? ((dy + ky)*34 + (dx + kx))*8 : 0;
  }
  float bias_r[4], sgn[4];
  #pragma unroll
  for (int nt = 0; nt < 4; ++nt) {
    const int c = nt*16 + ln;
    bias_r[nt] = bias[c];
    sgn[nt] = (gnw[c]*scale[c] >= 0.f) ? 1.f : -1.f;
  }
  float s[4]  = {0.f,0.f,0.f,0.f};
  float sq[4] = {0.f,0.f,0.f,0.f};
  _Float16* wext = (_Float16*)ws;

  #pragma unroll 2
  for (int i = 0; i < 16; ++i) {
    const int wyl = wave*2 + (i >> 3), wxl = i & 7;
    const int base = (wyl*4*34 + wxl*4)*8;
    f32x4 acc[4];
    #pragma unroll
    for (int nt = 0; nt < 4; ++nt) {
      const float bv = bias_r[nt];
      acc[nt] = (f32x4){bv, bv, bv, bv};
    }
    #pragma unroll
    for (int c = 0; c < 3; ++c) {
      const f16x8 a = *(const f16x8*)&xs[base + aoff[c]];
      #pragma unroll
      for (int nt = 0; nt < 4; ++nt)
        acc[nt] = __builtin_amdgcn_mfma_f32_16x16x32_f16(a, bf[nt][c], acc[nt], 0, 0, 0);
    }
    const int wyg = ty*8 + wyl, wxg = tx*8 + wxl;
    if ((wyg < PWN) && (wxg < PWN)) {
      const size_t rowbase = ((size_t)(b*PWN + wyg)*PWN + wxg)*COUT;
      float m4[4];
      #pragma unroll
      for (int nt = 0; nt < 4; ++nt) {
        const float v0 = acc[nt][0], v1 = acc[nt][1];
        const float v2 = acc[nt][2], v3 = acc[nt][3];
        s[nt]  += (v0+v1) + (v2+v3);
        sq[nt] += v0*v0 + v1*v1 + v2*v2 + v3*v3;
        const float sg = sgn[nt];
        float m = fmaxf(fmaxf(sg*v0, sg*v1), fmaxf(sg*v2, sg*v3));
        m = fmaxf(m, __shfl_xor(m, 16, 64));
        m = fmaxf(m, __shfl_xor(m, 32, 64));
        m4[nt] = sg*m;
      }
      float mv = m4[0];
      mv = (q == 1) ? m4[1] : mv;
      mv = (q == 2) ? m4[2] : mv;
      mv = (q == 3) ? m4[3] : mv;
      wext[rowbase + lane] = (_Float16)mv;
    } else {
      const bool yv = (wyg*4 + q) < OH;
      #pragma unroll
      for (int nt = 0; nt < 4; ++nt) {
        #pragma unroll
        for (int r = 0; r < 4; ++r) {
          const bool okp = yv && (wxg*4 + r < OW);
          const float v = okp ? acc[nt][r] : 0.f;
          s[nt] += v; sq[nt] += v*v;
        }
      }
    }
  }
  #pragma unroll
  for (int nt = 0; nt < 4; ++nt) {
    float a = s[nt], c2 = sq[nt];
    a  += __shfl_xor(a, 16, 64);  a  += __shfl_xor(a, 32, 64);
    a  += __shfl_xor(a, 1, 64);   a  += __shfl_xor(a, 2, 64);
    c2 += __shfl_xor(c2, 16, 64); c2 += __shfl_xor(c2, 32, 64);
    c2 += __shfl_xor(c2, 1, 64);  c2 += __shfl_xor(c2, 2, 64);
    if (lane < 16 && (lane & 3) == 0) {
      red[wave][nt*4 + (ln >> 2)][0] = a;
      red[wave][nt*4 + (ln >> 2)][1] = c2;
    }
  }
  __syncthreads();
  if (tid < 32) {
    const int g = tid >> 1, k = tid & 1;
    const float t = red[0][g][k] + red[1][g][k] + red[2][g][k] + red[3][g][k];
    ws[OFF_PART_OLD + (((size_t)b*NGROUPS + g)*16 + tileIdx)*2 + k] = t;
  }
}

// ============================================================
// Fused tail (parameterized partial count / pointers).
// ============================================================
__global__ __launch_bounds__(256)
void tail_kernel(const float* __restrict__ gnw,
                 const float* __restrict__ gnb,
                 const float* __restrict__ scale,
                 const _Float16* __restrict__ wext,
                 const float* __restrict__ parts,
                 const int nparts,
                 float* __restrict__ out)
{
  __shared__ float stat[NGROUPS*2];
  __shared__ float AB[128];
  __shared__ float vout[COUT*PWN];

  const int tid = threadIdx.x;
  const int xb  = blockIdx.x;
  const int b   = blockIdx.y;

  if (tid < 32) {
    const int g = tid >> 1, k = tid & 1;
    const float* p = parts + ((size_t)(b*NGROUPS + g)*nparts)*2 + k;
    float a = 0.f;
    for (int t = 0; t < nparts; ++t) a += p[t*2];
    stat[g*2 + k] = a;
  }
  __syncthreads();
  if (tid < COUT) {
    const int c = tid, g = c >> 2;
    const float N = (float)(CPG * OH * OW);
    const float mean = stat[g*2] / N;
    const float var  = stat[g*2 + 1] / N - mean*mean;
    const float inv  = rsqrtf(var + 1e-5f);
    const float ag   = inv * gnw[c];
    AB[c]      = ag * scale[c];
    AB[64 + c] = (gnb[c] - mean * ag) * scale[c];
  }
  __syncthreads();

  #pragma unroll
  for (int r = 0; r < 2; ++r) {
    const int wy = xb*2 + r;
    if (wy >= PWN) break;
    const size_t rb = (size_t)(b*PWN + wy)*PWN*COUT;

    if (tid < 248) {
      const f16x8 e = *(const f16x8*)&wext[rb + tid*8];
      const int wx = tid >> 3, c0 = (tid & 7)*8;
      #pragma unroll
      for (int j = 0; j < 8; ++j) {
        const int c = c0 + j;
        float v = fmaf(AB[c], (float)e[j], AB[64 + c]);
        v = fminf(fmaxf(v, 0.f), 1.f);
        vout[c*PWN + wx] = v;
      }
    }
    __syncthreads();
    for (int e = tid; e < COUT*PWN; e += 256) {
      const int c = e / PWN, wx = e - c*PWN;
      out[(((size_t)b*COUT + c)*PWN + wy)*PWN + wx] = vout[e];
    }
    __syncthreads();
  }
}

extern "C" void kernel_launch(void* const* d_in, const int* in_sizes, int n_in,
                              void* d_out, int out_size, void* d_ws, size_t ws_size,
                              hipStream_t stream)
{
  const float* x     = (const float*)d_in[0];
  const float* cw    = (const float*)d_in[1];
  const float* cb    = (const float*)d_in[2];
  const float* gnw   = (const float*)d_in[3];
  const float* gnb   = (const float*)d_in[4];
  const float* scale = (const float*)d_in[5];
  float* out = (float*)d_out;
  float* ws  = (float*)d_ws;

  if (ws_size >= WS_NEEDED) {
    _Float16* xh   = (_Float16*)ws;
    _Float16* wext = (_Float16*)((char*)ws + XH_BYTES);
    float*    prt  = (float*)((char*)ws + XH_BYTES + WEXT_BYTES);
    _Float16* wh   = (_Float16*)((char*)ws + XH_BYTES + WEXT_BYTES + PART_BYTES);

    xpack_kernel<<<dim3(XH_DIM + 1, NB), 192, 0, stream>>>(x, cw, xh, wh);
    conv_dma_kernel<<<dim3(4, NB), 512, 0, stream>>>(xh, wh, cb, gnw, scale, wext, prt);
    tail_kernel<<<dim3(16, NB), 256, 0, stream>>>(gnw, gnb, scale, wext, prt, 4, out);
  } else {
    conv_mfma_kernel<<<dim3(16, NB), 256, 0, stream>>>(x, cw, cb, gnw, scale, ws);
    tail_kernel<<<dim3(16, NB), 256, 0, stream>>>(gnw, gnb, scale,
                                                  (const _Float16*)ws,
                                                  ws + OFF_PART_OLD, 16, out);
  }
}